// Round 10
// baseline (323.401 us; speedup 1.0000x reference)
//
#include <hip/hip_runtime.h>
#include <hip/hip_bf16.h>

#define M_ROWS 16384
#define D_DIM  1024
#define K_CB   4096

#define MTILE  128               // z rows per block
#define CTILE  128               // cb entries per chunk
#define BK     64
#define NS     8
#define COLS_PER_SPLIT (K_CB / NS)         // 512
#define BODIES 64                          // 4 chunks x 16 K-bodies (K=1024/64)
#define MBLOCKS (M_ROWS / MTILE)           // 128

typedef __attribute__((ext_vector_type(8))) short short8;
typedef __attribute__((ext_vector_type(16))) float f32x16;

static __device__ __forceinline__ unsigned short f2bf(float f) {
  unsigned u = __float_as_uint(f);
  unsigned r = ((u >> 16) & 1u) + 0x7FFFu;   // RNE
  return (unsigned short)((u + r) >> 16);
}

static __device__ __forceinline__ unsigned f2sortable(float f) {
  unsigned u = __float_as_uint(f);
  return (u & 0x80000000u) ? ~u : (u | 0x80000000u);
}

static __device__ __forceinline__ float sortable2f(unsigned s) {
  unsigned u = (s & 0x80000000u) ? (s ^ 0x80000000u) : ~s;
  return __uint_as_float(u);
}

static __device__ __forceinline__ void gload_lds16(const unsigned short* g, unsigned short* l) {
  __builtin_amdgcn_global_load_lds(
      (const __attribute__((address_space(1))) void*)g,
      (__attribute__((address_space(3))) void*)l, 16, 0, 0);
}

// ---------------- Kernel 1: l2-normalize rows -> bf16 ----------------
__global__ __launch_bounds__(256)
void k_normalize(const float* __restrict__ z, const float* __restrict__ cb,
                 unsigned short* __restrict__ zf, unsigned short* __restrict__ cbf) {
  const int bid = blockIdx.x;
  const float* src;
  unsigned short* dst;
  if (bid < M_ROWS) {
    src = z + (size_t)bid * D_DIM;
    dst = zf + (size_t)bid * D_DIM;
  } else {
    const int r = bid - M_ROWS;
    src = cb + (size_t)r * D_DIM;
    dst = cbf + (size_t)r * D_DIM;
  }
  const int t = threadIdx.x;
  const float4 v = ((const float4*)src)[t];
  float ss = v.x * v.x + v.y * v.y + v.z * v.z + v.w * v.w;
#pragma unroll
  for (int off = 32; off > 0; off >>= 1) ss += __shfl_down(ss, off, 64);
  __shared__ float sp[4];
  if ((t & 63) == 0) sp[t >> 6] = ss;
  __syncthreads();
  const float tot = sp[0] + sp[1] + sp[2] + sp[3];
  const float invn = 1.0f / sqrtf(tot + 1e-12f);
  ushort4 o;
  o.x = f2bf(v.x * invn);
  o.y = f2bf(v.y * invn);
  o.z = f2bf(v.z * invn);
  o.w = f2bf(v.w * invn);
  ((ushort4*)dst)[t] = o;
}

// ---------------- Kernel 2: 128x128 tile, BK=64, 32x32x16 MFMA ----------------
// m97-replica: one barrier per body of {8 gload_lds16, 16 ds_read_b128,
// 16 MFMA} -> 512 cy/SIMD of MFMA cover per barrier drain (R9 had 256 cy per
// 2 barriers -> sync-bound at MfmaUtil 24%). 64 KB LDS dbuf -> 2 blocks/CU.
// Rows are 64 elems = 128 B: swizzle 16B-slot s' = s ^ (row&7) (m201's proven
// involution for 128B rows). Fragment read (row=l31 32 rows x slot kk*2+l5):
// quad = s' -> 8 lanes/quad = b128 floor.
__global__ __launch_bounds__(256, 2)
void k_gemm_topk(const unsigned short* __restrict__ zf,
                 const unsigned short* __restrict__ cbf,
                 unsigned* __restrict__ part) {
  __shared__ __align__(16) unsigned short smem[32768];  // 64 KB: Z0|Z1|C0|C1 16KB each

  const int tid  = threadIdx.x;
  const int lane = tid & 63;
  const int wid  = tid >> 6;
  const int wc   = wid & 1;    // cb 64-block
  const int wzz  = wid >> 1;   // z 64-block
  const int l31  = lane & 31;
  const int l5   = lane >> 5;

  const int wgid  = (int)blockIdx.x;
  const int split = wgid & 7;          // xcd-resident codebook slab
  const int mtile = wgid >> 3;
  const int rbase = mtile * MTILE;
  const int cbase = split * COLS_PER_SPLIT;

  // fragment elem offsets within one 8192-elem buffer:
  // row r (64 elems = 8 slots), want global slot w = kk*2+l5 -> read LDS slot
  // w ^ (r&7).
  int cAddr[2][4], zAddr[2][4];
#pragma unroll
  for (int mi = 0; mi < 2; ++mi) {
    const int r = wc * 64 + mi * 32 + l31;
#pragma unroll
    for (int kk = 0; kk < 4; ++kk)
      cAddr[mi][kk] = r * BK + ((((kk << 1) + l5) ^ (r & 7)) << 3);
  }
#pragma unroll
  for (int nj = 0; nj < 2; ++nj) {
    const int r = wzz * 64 + nj * 32 + l31;
#pragma unroll
    for (int kk = 0; kk < 4; ++kk)
      zAddr[nj][kk] = r * BK + ((((kk << 1) + l5) ^ (r & 7)) << 3);
  }

  // staging: thread t covers 16B slots {i*256+t}, i=0..3 per matrix.
  // slot_flat -> row = slot>>3 = i*32 + (t>>3), s = slot&7 = t&7.
  // LDS dest linear; global source pre-swizzled: slot s holds global slot
  // s^(row&7); row&7 = (t>>3)&7 for all i (i*32 === 0 mod 8).
  const long stoff = (long)(tid >> 3) * D_DIM + (((tid & 7) ^ ((tid >> 3) & 7)) << 3);

  // running stage pointers (at the NEXT body to stage)
  const unsigned short* zsp = zf + (size_t)rbase * D_DIM + stoff;
  const unsigned short* csp = cbf + (size_t)cbase * D_DIM + stoff;

  f32x16 acc[2][2];
#pragma unroll
  for (int mi = 0; mi < 2; ++mi)
#pragma unroll
    for (int nj = 0; nj < 2; ++nj)
#pragma unroll
      for (int r = 0; r < 16; ++r) acc[mi][nj][r] = 0.f;

  unsigned tk[2][8];
  unsigned tkmin[2];
  float    tminf[2];
#pragma unroll
  for (int l = 0; l < 2; ++l) {
    tkmin[l] = 0u;
    tminf[l] = -__builtin_inff();
#pragma unroll
    for (int q = 0; q < 8; ++q) tk[l][q] = 0u;
  }

  auto STAGE = [&](int par) {
    unsigned short* zd = smem + (par ? 8192 : 0) + tid * 8;
    unsigned short* cd = smem + 16384 + (par ? 8192 : 0) + tid * 8;
#pragma unroll
    for (int i = 0; i < 4; ++i) {
      gload_lds16(zsp + (size_t)i * 32 * D_DIM, zd + i * 2048);
      gload_lds16(csp + (size_t)i * 32 * D_DIM, cd + i * 2048);
    }
  };
  auto COMPUTE = [&](int par) {
    const unsigned short* Z = smem + (par ? 8192 : 0);
    const unsigned short* C = smem + 16384 + (par ? 8192 : 0);
    short8 cf[2][4], zr[2][4];
#pragma unroll
    for (int mi = 0; mi < 2; ++mi)
#pragma unroll
      for (int kk = 0; kk < 4; ++kk) cf[mi][kk] = *(const short8*)(C + cAddr[mi][kk]);
#pragma unroll
    for (int nj = 0; nj < 2; ++nj)
#pragma unroll
      for (int kk = 0; kk < 4; ++kk) zr[nj][kk] = *(const short8*)(Z + zAddr[nj][kk]);
#pragma unroll
    for (int kk = 0; kk < 4; ++kk)
#pragma unroll
      for (int mi = 0; mi < 2; ++mi)
#pragma unroll
        for (int nj = 0; nj < 2; ++nj)
          acc[mi][nj] = __builtin_amdgcn_mfma_f32_32x32x16_bf16(
              cf[mi][kk], zr[nj][kk], acc[mi][nj], 0, 0, 0);
  };
  auto EPILOGUE = [&](int chunk) {
    const int cfb0 = cbase + chunk * CTILE + wc * 64 + l5 * 4;
#pragma unroll
    for (int nj = 0; nj < 2; ++nj) {
#pragma unroll
      for (int mi = 0; mi < 2; ++mi) {
#pragma unroll
        for (int r = 0; r < 16; ++r) {
          const float v = acc[mi][nj][r];
          // must be !(v <= t): tminf is NaN while table has empty slots ->
          // fall through to exact u32 check ((v > NaN) starves; R2 bug).
          if (!(v <= tminf[nj])) {
            // 32x32 C/D: cb = (r&3) + 8*(r>>2) + 4*l5 within the mi-block
            const unsigned idx = (unsigned)(cfb0 + mi * 32 + (r & 3) + ((r >> 2) << 3));
            const unsigned key = (f2sortable(v) & ~0xFFFu) | idx;
            if (key > tkmin[nj]) {
              int ms = 0;
              unsigned mv = tk[nj][0];
#pragma unroll
              for (int q = 1; q < 8; ++q) { if (tk[nj][q] < mv) { mv = tk[nj][q]; ms = q; } }
#pragma unroll
              for (int q = 0; q < 8; ++q) tk[nj][q] = (q == ms) ? key : tk[nj][q];
              mv = tk[nj][0];
#pragma unroll
              for (int q = 1; q < 8; ++q) mv = (tk[nj][q] < mv) ? tk[nj][q] : mv;
              tkmin[nj] = mv;
              tminf[nj] = sortable2f(mv & ~0xFFFu);
            }
          }
          acc[mi][nj][r] = 0.f;
        }
      }
    }
  };

  // prologue: stage body 0 -> buf0; advance to body 1 (no chunk jump at 1)
  STAGE(0);
  zsp += BK; csp += BK;
  __syncthreads();

  for (int b = 0; b < BODIES; b += 2) {
    // even slot: stage body b+1 -> buf1, compute body b (buf0)
    STAGE(1);
    zsp += BK; csp += BK;
    if (((b + 2) & 15) == 0) {             // next body starts a new chunk
      zsp -= D_DIM;                        // Z k-tiles repeat every chunk
      csp += CTILE * D_DIM - D_DIM;        // C advances to next 128-entry slab
    }
    COMPUTE(0);
    __syncthreads();

    // odd slot: stage body b+2 -> buf0 (if any), compute body b+1 (buf1)
    if (b + 2 < BODIES) {
      STAGE(0);
      zsp += BK; csp += BK;                // b+3 odd -> never a chunk start
    }
    COMPUTE(1);
    if ((b & 15) == 14) EPILOGUE(b >> 4);  // chunk completes at bodies 15/31/47/63
    __syncthreads();
  }

  // merge: per z row 4 contributors (wc x l5) x 8 keys -> LDS, then top-8 scan
  unsigned* mrg = (unsigned*)smem;     // [128][33] u32 = 16.9 KB
  {
    const int slot = (wc * 2 + l5) * 8;
#pragma unroll
    for (int nj = 0; nj < 2; ++nj) {
      const int zrow = wzz * 64 + nj * 32 + l31;
#pragma unroll
      for (int q = 0; q < 8; ++q) mrg[zrow * 33 + slot + q] = tk[nj][q];
    }
  }
  __syncthreads();
  if (tid < MTILE) {
    const unsigned* c = mrg + tid * 33;
    unsigned top[8];
#pragma unroll
    for (int p = 0; p < 8; ++p) top[p] = 0u;
    unsigned tmin = 0u;
    for (int q0 = 0; q0 < 32; ++q0) {
      const unsigned k = c[(q0 + tid) & 31];   // rotate to spread banks
      if (k > tmin) {
        int ms = 0;
        unsigned mv = top[0];
#pragma unroll
        for (int q = 1; q < 8; ++q) { if (top[q] < mv) { mv = top[q]; ms = q; } }
#pragma unroll
        for (int q = 0; q < 8; ++q) top[q] = (q == ms) ? k : top[q];
        mv = top[0];
#pragma unroll
        for (int q = 1; q < 8; ++q) mv = (top[q] < mv) ? top[q] : mv;
        tmin = mv;
      }
    }
    unsigned* dst = part + ((size_t)(rbase + tid) * NS + split) * 8;
#pragma unroll
    for (int p = 0; p < 8; ++p) dst[p] = top[p];
  }
}

// ---------------- Kernel 3: merge splits, softmax, gather E, gate ----------------
template<int NSP>
__global__ __launch_bounds__(256)
void k_gate(const unsigned* __restrict__ part, const float* __restrict__ target,
            const float* __restrict__ E, float* __restrict__ out) {
  constexpr int NK = NSP * 8;
  const int row = blockIdx.x;
  const int t = threadIdx.x;
  __shared__ float s_alpha[8];
  __shared__ int s_idx[8];
  __shared__ unsigned s_key[8];

  if (t < NK) {
    unsigned k = part[(size_t)row * NK + t];
#pragma unroll
    for (int p = 0; p < 8; ++p) {
      unsigned m = k;
#pragma unroll
      for (int off = NK / 2; off > 0; off >>= 1) {
        const unsigned o = __shfl_xor(m, off, NK);
        m = (m > o) ? m : o;
      }
      if (k == m) { s_key[p] = k; k = 0u; }  // keys distinct (idx in low bits)
    }
  }
  __syncthreads();
  if (t < 8) {
    const unsigned key = s_key[t];
    const float val  = 10.0f * sortable2f(key & ~0xFFFu);
    const float vmax = 10.0f * sortable2f(s_key[0] & ~0xFFFu);
    const float e = expf(val - vmax);
    float s = e;
#pragma unroll
    for (int off = 4; off > 0; off >>= 1) s += __shfl_xor(s, off, 8);
    s_alpha[t] = e / s;
    s_idx[t] = (int)(key & 0xFFFu);
  }
  __syncthreads();

  float4 g = {0.f, 0.f, 0.f, 0.f};
#pragma unroll
  for (int p = 0; p < 8; ++p) {
    const float a = s_alpha[p];
    const float4 e4 = ((const float4*)E)[(size_t)s_idx[p] * 256 + t];
    g.x += a * e4.x;
    g.y += a * e4.y;
    g.z += a * e4.z;
    g.w += a * e4.w;
  }
  const float4 tg = ((const float4*)target)[(size_t)row * 256 + t];
  float4 o;
  o.x = tg.x * (1.f + g.x);
  o.y = tg.y * (1.f + g.y);
  o.z = tg.z * (1.f + g.z);
  o.w = tg.w * (1.f + g.w);
  ((float4*)out)[(size_t)row * 256 + t] = o;
}

extern "C" void kernel_launch(void* const* d_in, const int* in_sizes, int n_in,
                              void* d_out, int out_size, void* d_ws, size_t ws_size,
                              hipStream_t stream) {
  const float* z      = (const float*)d_in[0];
  const float* target = (const float*)d_in[1];
  const float* cb     = (const float*)d_in[2];
  const float* E      = (const float*)d_in[3];
  float* out = (float*)d_out;

  // d_out doubles as scratch for the bf16 normalized matrices (dead before k_gate writes)
  unsigned short* zf  = (unsigned short*)d_out;                       // 32 MB
  unsigned short* cbf = (unsigned short*)((char*)d_out + 33554432);   // 8 MB @ +32MB
  unsigned* part = (unsigned*)d_ws;                                   // 4 MB

  k_normalize<<<dim3(M_ROWS + K_CB), dim3(256), 0, stream>>>(z, cb, zf, cbf);
  k_gemm_topk<<<dim3(MBLOCKS * NS), dim3(256), 0, stream>>>(zf, cbf, part);
  k_gate<NS><<<dim3(M_ROWS), dim3(256), 0, stream>>>(part, target, E, out);
}

// Round 12
// 311.696 us; speedup vs baseline: 1.0376x; 1.0376x over previous
//
#include <hip/hip_runtime.h>
#include <hip/hip_bf16.h>

#define M_ROWS 16384
#define D_DIM  1024
#define K_CB   4096

#define MTILE  128               // z rows per block
#define CTILE  128               // cb entries per chunk
#define BK     32
#define NS     8
#define COLS_PER_SPLIT (K_CB / NS)         // 512
#define BODIES 128                         // 4 chunks x 32 K-bodies
#define MBLOCKS (M_ROWS / MTILE)           // 128
#define SLOT_E 4096                        // elems per slot (128 rows x 32)

typedef __attribute__((ext_vector_type(8))) short short8;
typedef __attribute__((ext_vector_type(16))) float f32x16;

static __device__ __forceinline__ unsigned short f2bf(float f) {
  unsigned u = __float_as_uint(f);
  unsigned r = ((u >> 16) & 1u) + 0x7FFFu;   // RNE
  return (unsigned short)((u + r) >> 16);
}

static __device__ __forceinline__ unsigned f2sortable(float f) {
  unsigned u = __float_as_uint(f);
  return (u & 0x80000000u) ? ~u : (u | 0x80000000u);
}

static __device__ __forceinline__ float sortable2f(unsigned s) {
  unsigned u = (s & 0x80000000u) ? (s ^ 0x80000000u) : ~s;
  return __uint_as_float(u);
}

static __device__ __forceinline__ void gload_lds16(const unsigned short* g, unsigned short* l) {
  __builtin_amdgcn_global_load_lds(
      (const __attribute__((address_space(1))) void*)g,
      (__attribute__((address_space(3))) void*)l, 16, 0, 0);
}

// ---------------- Kernel 1: l2-normalize rows -> bf16 ----------------
__global__ __launch_bounds__(256)
void k_normalize(const float* __restrict__ z, const float* __restrict__ cb,
                 unsigned short* __restrict__ zf, unsigned short* __restrict__ cbf) {
  const int bid = blockIdx.x;
  const float* src;
  unsigned short* dst;
  if (bid < M_ROWS) {
    src = z + (size_t)bid * D_DIM;
    dst = zf + (size_t)bid * D_DIM;
  } else {
    const int r = bid - M_ROWS;
    src = cb + (size_t)r * D_DIM;
    dst = cbf + (size_t)r * D_DIM;
  }
  const int t = threadIdx.x;
  const float4 v = ((const float4*)src)[t];
  float ss = v.x * v.x + v.y * v.y + v.z * v.z + v.w * v.w;
#pragma unroll
  for (int off = 32; off > 0; off >>= 1) ss += __shfl_down(ss, off, 64);
  __shared__ float sp[4];
  if ((t & 63) == 0) sp[t >> 6] = ss;
  __syncthreads();
  const float tot = sp[0] + sp[1] + sp[2] + sp[3];
  const float invn = 1.0f / sqrtf(tot + 1e-12f);
  ushort4 o;
  o.x = f2bf(v.x * invn);
  o.y = f2bf(v.y * invn);
  o.z = f2bf(v.z * invn);
  o.w = f2bf(v.w * invn);
  ((ushort4*)dst)[t] = o;
}

// ---------------- Kernel 2: BK=32, 32x32x16, 3-slot ring, counted vmcnt ----------------
// R9 geometry (best so far) but the per-body __syncthreads drain (vmcnt(0)
// every ~300cy) replaced by a 3-slot ring: stage body b+2 each iter, raw
// s_barrier with vmcnt(4) -> next body's data landed, newest stage stays in
// flight. 48 KB LDS -> 3 blocks/CU (12 waves). Ring hazard: stage@b targets
// slot (b+2)%3 = slot read at b-1, whose reads finished before b-1's end
// barrier. R11 BUG (fixed): sdBase advanced with the READ-slot delta ->
// walked 2,3,4 slots (C-region clobber + OOB). Stage base needs its OWN wrap:
// dS = (sdBase < 2*SLOT_E) ? +SLOT_E : -2*SLOT_E  ->  2,0,1,2,... = (b+2)%3.
__global__ __launch_bounds__(256, 3)
void k_gemm_topk(const unsigned short* __restrict__ zf,
                 const unsigned short* __restrict__ cbf,
                 unsigned* __restrict__ part) {
  __shared__ __align__(16) unsigned short smem[3 * SLOT_E * 2];  // 48 KB: Z s0..2 | C s0..2

  const int tid  = threadIdx.x;
  const int lane = tid & 63;
  const int wid  = tid >> 6;
  const int wc   = wid & 1;    // cb 64-block
  const int wzz  = wid >> 1;   // z 64-block
  const int l31  = lane & 31;
  const int l5   = lane >> 5;

  const int wgid  = (int)blockIdx.x;
  const int split = wgid & 7;          // xcd-resident codebook slab
  const int mtile = wgid >> 3;
  const int rbase = mtile * MTILE;
  const int cbase = split * COLS_PER_SPLIT;

  // fragment elem offsets (slot 0): row r, 16B slot s = kk*2+l5, swz s^((r>>1)&3)
  // loop-carried, advanced by the read-slot ring delta; static indexing only.
  int co[2][2], zo[2][2];
#pragma unroll
  for (int mi = 0; mi < 2; ++mi) {
    const int r = wc * 64 + mi * 32 + l31;
#pragma unroll
    for (int kk = 0; kk < 2; ++kk)
      co[mi][kk] = 3 * SLOT_E + r * BK + ((((kk << 1) + l5) ^ ((r >> 1) & 3)) << 3);
  }
#pragma unroll
  for (int nj = 0; nj < 2; ++nj) {
    const int r = wzz * 64 + nj * 32 + l31;
#pragma unroll
    for (int kk = 0; kk < 2; ++kk)
      zo[nj][kk] = r * BK + ((((kk << 1) + l5) ^ ((r >> 1) & 3)) << 3);
  }

  // staging: thread -> 16B slots tid (row tid>>2) and tid+256 (row+64), LDS
  // linear; global source pre-swizzled with the same involution
  // (s' = s ^ ((row>>1)&3), row = tid>>2 -> xor term ((tid>>3)&3)).
  const long stoff = (long)(tid >> 2) * D_DIM + (((tid & 3) ^ ((tid >> 3) & 3)) << 3);

  const unsigned short* zsp = zf + (size_t)rbase * D_DIM + stoff;
  const unsigned short* csp = cbf + (size_t)cbase * D_DIM + stoff;

  f32x16 acc[2][2];
#pragma unroll
  for (int mi = 0; mi < 2; ++mi)
#pragma unroll
    for (int nj = 0; nj < 2; ++nj)
#pragma unroll
      for (int r = 0; r < 16; ++r) acc[mi][nj][r] = 0.f;

  // top-8 tables, sorted ascending (tk[0] = current min)
  unsigned tk[2][8];
  float    tminf[2];
#pragma unroll
  for (int l = 0; l < 2; ++l) {
    tminf[l] = -__builtin_inff();
#pragma unroll
    for (int q = 0; q < 8; ++q) tk[l][q] = 0u;
  }

  auto STAGE_AT = [&](int dstBase) {
    gload_lds16(zsp,                 smem + dstBase + tid * 8);
    gload_lds16(zsp + 64 * D_DIM,    smem + dstBase + 2048 + tid * 8);
    gload_lds16(csp,                 smem + dstBase + 3 * SLOT_E + tid * 8);
    gload_lds16(csp + 64 * D_DIM,    smem + dstBase + 3 * SLOT_E + 2048 + tid * 8);
  };
  auto ADV = [&](int stagedBody) {   // prep pointers for body stagedBody+1
    if (((stagedBody + 1) & 31) == 0) {
      zsp += BK - D_DIM;                       // Z k-tiles repeat each chunk
      csp += BK + (CTILE * D_DIM - D_DIM);     // C -> next 128-entry slab
    } else {
      zsp += BK; csp += BK;
    }
  };

  auto EPILOGUE = [&](int chunk) {
    const int cfb0 = cbase + chunk * CTILE + wc * 64 + l5 * 4;
#pragma unroll
    for (int nj = 0; nj < 2; ++nj) {
#pragma unroll
      for (int mi = 0; mi < 2; ++mi) {
#pragma unroll
        for (int rq = 0; rq < 4; ++rq) {
          const float v0 = acc[mi][nj][4 * rq + 0];
          const float v1 = acc[mi][nj][4 * rq + 1];
          const float v2 = acc[mi][nj][4 * rq + 2];
          const float v3 = acc[mi][nj][4 * rq + 3];
          const float gmax = fmaxf(fmaxf(v0, v1), fmaxf(v2, v3));
          // must be !(g <= t): tminf is NaN while table has empty slots ->
          // always enter ((g > NaN) would starve; R2 bug family).
          if (!(gmax <= tminf[nj])) {
#pragma unroll
            for (int ri = 0; ri < 4; ++ri) {
              const int r = 4 * rq + ri;
              const float v = acc[mi][nj][r];
              if (!(v <= tminf[nj])) {
                const unsigned idx = (unsigned)(cfb0 + mi * 32 + (r & 3) + ((r >> 2) << 3));
                const unsigned key = (f2sortable(v) & ~0xFFFu) | idx;
                if (key > tk[nj][0]) {         // replace current min, keep sorted
                  unsigned cur = key;
#pragma unroll
                  for (int q = 0; q < 7; ++q) {
                    const unsigned a = tk[nj][q + 1];
                    tk[nj][q] = (a < cur) ? a : cur;
                    cur       = (a < cur) ? cur : a;
                  }
                  tk[nj][7] = cur;
                  tminf[nj] = sortable2f(tk[nj][0] & ~0xFFFu);
                }
              }
            }
          }
          acc[mi][nj][4 * rq + 0] = 0.f;
          acc[mi][nj][4 * rq + 1] = 0.f;
          acc[mi][nj][4 * rq + 2] = 0.f;
          acc[mi][nj][4 * rq + 3] = 0.f;
        }
      }
    }
  };

  // prologue: stage bodies 0,1 into slots 0,1; body 0 (oldest 4) must land
  STAGE_AT(0);          ADV(0);
  STAGE_AT(SLOT_E);     ADV(1);
  asm volatile("s_waitcnt vmcnt(4)" ::: "memory");
  __builtin_amdgcn_s_barrier();
  __builtin_amdgcn_sched_barrier(0);

  int slot   = 0;            // read slot index (wave-uniform)
  int sdBase = 2 * SLOT_E;   // stage dest base; cycles 2,0,1,2,... = (b+2)%3
  for (int b = 0; b < BODIES; ++b) {
    short8 cf[2][2], zr[2][2];
#pragma unroll
    for (int mi = 0; mi < 2; ++mi)
#pragma unroll
      for (int kk = 0; kk < 2; ++kk) cf[mi][kk] = *(const short8*)(smem + co[mi][kk]);
#pragma unroll
    for (int nj = 0; nj < 2; ++nj)
#pragma unroll
      for (int kk = 0; kk < 2; ++kk) zr[nj][kk] = *(const short8*)(smem + zo[nj][kk]);

    if (b + 2 < BODIES) {           // stage body b+2 into slot (b+2)%3
      STAGE_AT(sdBase);
      ADV(b + 2);
    }

    asm volatile("s_waitcnt lgkmcnt(0)" ::: "memory");
    __builtin_amdgcn_sched_barrier(0);
    __builtin_amdgcn_s_setprio(1);
#pragma unroll
    for (int kk = 0; kk < 2; ++kk)
#pragma unroll
      for (int mi = 0; mi < 2; ++mi)
#pragma unroll
        for (int nj = 0; nj < 2; ++nj)
          acc[mi][nj] = __builtin_amdgcn_mfma_f32_32x32x16_bf16(
              cf[mi][kk], zr[nj][kk], acc[mi][nj], 0, 0, 0);
    __builtin_amdgcn_s_setprio(0);

    if ((b & 31) == 31) EPILOGUE(b >> 5);

    // counted checkpoint: newest stage (body b+2) stays in flight; body b+1
    // (issued last iter) must land. Tail (no stage issued): drain.
    if (b + 2 < BODIES) asm volatile("s_waitcnt vmcnt(4)" ::: "memory");
    else                asm volatile("s_waitcnt vmcnt(0)" ::: "memory");
    __builtin_amdgcn_s_barrier();
    __builtin_amdgcn_sched_barrier(0);

    // advance read-slot offsets (wave-uniform deltas, static-indexed arrays)
    const int dR = (slot < 2) ? SLOT_E : -2 * SLOT_E;
#pragma unroll
    for (int mi = 0; mi < 2; ++mi)
#pragma unroll
      for (int kk = 0; kk < 2; ++kk) co[mi][kk] += dR;
#pragma unroll
    for (int nj = 0; nj < 2; ++nj)
#pragma unroll
      for (int kk = 0; kk < 2; ++kk) zo[nj][kk] += dR;
    slot = (slot < 2) ? slot + 1 : 0;
    // stage base has its OWN wrap (R11 bug fix): 2,0,1,2,...
    sdBase += (sdBase < 2 * SLOT_E) ? SLOT_E : -2 * SLOT_E;
  }

  // merge: per z row 4 contributors (wc x l5) x 8 keys -> LDS, then top-8 scan
  __syncthreads();
  unsigned* mrg = (unsigned*)smem;     // [128][33] u32 = 16.9 KB
  {
    const int slotw = (wc * 2 + l5) * 8;
#pragma unroll
    for (int nj = 0; nj < 2; ++nj) {
      const int zrow = wzz * 64 + nj * 32 + l31;
#pragma unroll
      for (int q = 0; q < 8; ++q) mrg[zrow * 33 + slotw + q] = tk[nj][q];
    }
  }
  __syncthreads();
  if (tid < MTILE) {
    const unsigned* c = mrg + tid * 33;
    unsigned top[8];
#pragma unroll
    for (int p = 0; p < 8; ++p) top[p] = 0u;
    unsigned tmin = 0u;
    for (int q0 = 0; q0 < 32; ++q0) {
      const unsigned k = c[(q0 + tid) & 31];   // rotate to spread banks
      if (k > tmin) {
        int ms = 0;
        unsigned mv = top[0];
#pragma unroll
        for (int q = 1; q < 8; ++q) { if (top[q] < mv) { mv = top[q]; ms = q; } }
#pragma unroll
        for (int q = 0; q < 8; ++q) top[q] = (q == ms) ? k : top[q];
        mv = top[0];
#pragma unroll
        for (int q = 1; q < 8; ++q) mv = (top[q] < mv) ? top[q] : mv;
        tmin = mv;
      }
    }
    unsigned* dst = part + ((size_t)(rbase + tid) * NS + split) * 8;
#pragma unroll
    for (int p = 0; p < 8; ++p) dst[p] = top[p];
  }
}

// ---------------- Kernel 3: merge splits, softmax, gather E, gate ----------------
template<int NSP>
__global__ __launch_bounds__(256)
void k_gate(const unsigned* __restrict__ part, const float* __restrict__ target,
            const float* __restrict__ E, float* __restrict__ out) {
  constexpr int NK = NSP * 8;
  const int row = blockIdx.x;
  const int t = threadIdx.x;
  __shared__ float s_alpha[8];
  __shared__ int s_idx[8];
  __shared__ unsigned s_key[8];

  if (t < NK) {
    unsigned k = part[(size_t)row * NK + t];
#pragma unroll
    for (int p = 0; p < 8; ++p) {
      unsigned m = k;
#pragma unroll
      for (int off = NK / 2; off > 0; off >>= 1) {
        const unsigned o = __shfl_xor(m, off, NK);
        m = (m > o) ? m : o;
      }
      if (k == m) { s_key[p] = k; k = 0u; }  // keys distinct (idx in low bits)
    }
  }
  __syncthreads();
  if (t < 8) {
    const unsigned key = s_key[t];
    const float val  = 10.0f * sortable2f(key & ~0xFFFu);
    const float vmax = 10.0f * sortable2f(s_key[0] & ~0xFFFu);
    const float e = expf(val - vmax);
    float s = e;
#pragma unroll
    for (int off = 4; off > 0; off >>= 1) s += __shfl_xor(s, off, 8);
    s_alpha[t] = e / s;
    s_idx[t] = (int)(key & 0xFFFu);
  }
  __syncthreads();

  float4 g = {0.f, 0.f, 0.f, 0.f};
#pragma unroll
  for (int p = 0; p < 8; ++p) {
    const float a = s_alpha[p];
    const float4 e4 = ((const float4*)E)[(size_t)s_idx[p] * 256 + t];
    g.x += a * e4.x;
    g.y += a * e4.y;
    g.z += a * e4.z;
    g.w += a * e4.w;
  }
  const float4 tg = ((const float4*)target)[(size_t)row * 256 + t];
  float4 o;
  o.x = tg.x * (1.f + g.x);
  o.y = tg.y * (1.f + g.y);
  o.z = tg.z * (1.f + g.z);
  o.w = tg.w * (1.f + g.w);
  ((float4*)out)[(size_t)row * 256 + t] = o;
}

extern "C" void kernel_launch(void* const* d_in, const int* in_sizes, int n_in,
                              void* d_out, int out_size, void* d_ws, size_t ws_size,
                              hipStream_t stream) {
  const float* z      = (const float*)d_in[0];
  const float* target = (const float*)d_in[1];
  const float* cb     = (const float*)d_in[2];
  const float* E      = (const float*)d_in[3];
  float* out = (float*)d_out;

  // d_out doubles as scratch for the bf16 normalized matrices (dead before k_gate writes)
  unsigned short* zf  = (unsigned short*)d_out;                       // 32 MB
  unsigned short* cbf = (unsigned short*)((char*)d_out + 33554432);   // 8 MB @ +32MB
  unsigned* part = (unsigned*)d_ws;                                   // 4 MB

  k_normalize<<<dim3(M_ROWS + K_CB), dim3(256), 0, stream>>>(z, cb, zf, cbf);
  k_gemm_topk<<<dim3(MBLOCKS * NS), dim3(256), 0, stream>>>(zf, cbf, part);
  k_gate<NS><<<dim3(M_ROWS), dim3(256), 0, stream>>>(part, target, E, out);
}

// Round 13
// 298.084 us; speedup vs baseline: 1.0849x; 1.0457x over previous
//
#include <hip/hip_runtime.h>
#include <hip/hip_bf16.h>

#define M_ROWS 16384
#define D_DIM  1024
#define K_CB   4096

#define MTILE  256               // z rows per block
#define CTILE  256               // cb entries per chunk
#define BK     32
#define NS     8
#define COLS_PER_SPLIT (K_CB / NS)         // 512
#define KSTEPS (D_DIM / BK)                // 32
#define BODIES 64                          // 2 chunks x 32 K-steps
#define MBLOCKS (M_ROWS / MTILE)           // 64

typedef __attribute__((ext_vector_type(8))) short short8;
typedef __attribute__((ext_vector_type(16))) float f32x16;

static __device__ __forceinline__ unsigned short f2bf(float f) {
  unsigned u = __float_as_uint(f);
  unsigned r = ((u >> 16) & 1u) + 0x7FFFu;   // RNE
  return (unsigned short)((u + r) >> 16);
}

static __device__ __forceinline__ unsigned f2sortable(float f) {
  unsigned u = __float_as_uint(f);
  return (u & 0x80000000u) ? ~u : (u | 0x80000000u);
}

static __device__ __forceinline__ float sortable2f(unsigned s) {
  unsigned u = (s & 0x80000000u) ? (s ^ 0x80000000u) : ~s;
  return __uint_as_float(u);
}

static __device__ __forceinline__ void gload_lds16(const unsigned short* g, unsigned short* l) {
  __builtin_amdgcn_global_load_lds(
      (const __attribute__((address_space(1))) void*)g,
      (__attribute__((address_space(3))) void*)l, 16, 0, 0);
}

// ---------------- Kernel 1: l2-normalize rows -> bf16 ----------------
__global__ __launch_bounds__(256)
void k_normalize(const float* __restrict__ z, const float* __restrict__ cb,
                 unsigned short* __restrict__ zf, unsigned short* __restrict__ cbf) {
  const int bid = blockIdx.x;
  const float* src;
  unsigned short* dst;
  if (bid < M_ROWS) {
    src = z + (size_t)bid * D_DIM;
    dst = zf + (size_t)bid * D_DIM;
  } else {
    const int r = bid - M_ROWS;
    src = cb + (size_t)r * D_DIM;
    dst = cbf + (size_t)r * D_DIM;
  }
  const int t = threadIdx.x;
  const float4 v = ((const float4*)src)[t];
  float ss = v.x * v.x + v.y * v.y + v.z * v.z + v.w * v.w;
#pragma unroll
  for (int off = 32; off > 0; off >>= 1) ss += __shfl_down(ss, off, 64);
  __shared__ float sp[4];
  if ((t & 63) == 0) sp[t >> 6] = ss;
  __syncthreads();
  const float tot = sp[0] + sp[1] + sp[2] + sp[3];
  const float invn = 1.0f / sqrtf(tot + 1e-12f);
  ushort4 o;
  o.x = f2bf(v.x * invn);
  o.y = f2bf(v.y * invn);
  o.z = f2bf(v.z * invn);
  o.w = f2bf(v.w * invn);
  ((ushort4*)dst)[t] = o;
}

// ---------------- Kernel 2: 256x256 tile, BK=32, 32x32x16, dbuf+syncthreads ----------------
// 8 waves (wc in {0,1} cb-dir x wz in {0..3} z-dir); per wave 128cb x 64z =
// 4x2 MFMA-32 tiles, 16 MFMA/body = 512 cy/SIMD x 2 waves/SIMD = ~1024 cy
// MFMA wall per body >= HBM latency -> plain compiler-scheduled dbuf hides
// staging (R8/R9 proven skeleton; no manual vmcnt). 64 KB LDS, 1 block/CU,
// grid 512 = 2.0 blocks/CU sequential (no tail).
// Swizzle (R12-refchecked): 16B slot s' = s ^ ((row>>1)&3).
__global__ __launch_bounds__(512, 2)
void k_gemm_topk(const unsigned short* __restrict__ zf,
                 const unsigned short* __restrict__ cbf,
                 unsigned* __restrict__ part) {
  __shared__ __align__(16) unsigned short smem[32768];  // 64 KB: Z0|Z1|C0|C1 16KB each

  const int tid  = threadIdx.x;
  const int lane = tid & 63;
  const int wid  = tid >> 6;
  const int wc   = wid & 1;    // cb 128-block
  const int wz   = wid >> 1;   // z 64-block
  const int l31  = lane & 31;
  const int l5   = lane >> 5;

  const int wgid  = (int)blockIdx.x;
  const int split = wgid & 7;          // xcd-resident codebook slab
  const int mtile = wgid >> 3;
  const int rbase = mtile * MTILE;
  const int cbase = split * COLS_PER_SPLIT;

  // fragment elem offsets: row r, 16B slot w = kk*2+l5, read slot w^((r>>1)&3)
  int cAddr[4][2], zAddr[2][2];
#pragma unroll
  for (int mi = 0; mi < 4; ++mi) {
    const int r = wc * 128 + mi * 32 + l31;
#pragma unroll
    for (int kk = 0; kk < 2; ++kk)
      cAddr[mi][kk] = r * BK + ((((kk << 1) + l5) ^ ((r >> 1) & 3)) << 3);
  }
#pragma unroll
  for (int nj = 0; nj < 2; ++nj) {
    const int r = wz * 64 + nj * 32 + l31;
#pragma unroll
    for (int kk = 0; kk < 2; ++kk)
      zAddr[nj][kk] = r * BK + ((((kk << 1) + l5) ^ ((r >> 1) & 3)) << 3);
  }

  // staging: thread -> 16B slots tid (row tid>>2) and tid+512 (row+128), LDS
  // linear; global source pre-swizzled with the same involution
  // (s' = s ^ ((row>>1)&3), row = tid>>2 -> xor term ((tid>>3)&3); row+128
  // preserves it).
  const long stoff = (long)(tid >> 2) * D_DIM + (((tid & 3) ^ ((tid >> 3) & 3)) << 3);

  const unsigned short* zsp = zf + (size_t)rbase * D_DIM + stoff;
  const unsigned short* csp = cbf + (size_t)cbase * D_DIM + stoff;

  f32x16 acc[4][2];
#pragma unroll
  for (int mi = 0; mi < 4; ++mi)
#pragma unroll
    for (int nj = 0; nj < 2; ++nj)
#pragma unroll
      for (int r = 0; r < 16; ++r) acc[mi][nj][r] = 0.f;

  // top-8 tables, sorted ascending (tk[0] = current min)
  unsigned tk[2][8];
  float    tminf[2];
#pragma unroll
  for (int l = 0; l < 2; ++l) {
    tminf[l] = -__builtin_inff();
#pragma unroll
    for (int q = 0; q < 8; ++q) tk[l][q] = 0u;
  }

  auto STAGE = [&](int par) {
    unsigned short* zd = smem + (par ? 8192 : 0) + tid * 8;
    unsigned short* cd = smem + 16384 + (par ? 8192 : 0) + tid * 8;
    gload_lds16(zsp,                  zd);
    gload_lds16(zsp + 128 * D_DIM,    zd + 4096);
    gload_lds16(csp,                  cd);
    gload_lds16(csp + 128 * D_DIM,    cd + 4096);
  };
  auto ADV = [&](int stagedBody) {   // prep pointers for body stagedBody+1
    if (((stagedBody + 1) & 31) == 0) {
      zsp += BK - D_DIM;                       // Z k-tiles repeat each chunk
      csp += BK + (CTILE * D_DIM - D_DIM);     // C -> next 256-entry slab
    } else {
      zsp += BK; csp += BK;
    }
  };
  auto COMPUTE = [&](int par) {
    const unsigned short* Z = smem + (par ? 8192 : 0);
    const unsigned short* C = smem + 16384 + (par ? 8192 : 0);
    short8 cf[4][2], zr[2][2];
#pragma unroll
    for (int mi = 0; mi < 4; ++mi)
#pragma unroll
      for (int kk = 0; kk < 2; ++kk) cf[mi][kk] = *(const short8*)(C + cAddr[mi][kk]);
#pragma unroll
    for (int nj = 0; nj < 2; ++nj)
#pragma unroll
      for (int kk = 0; kk < 2; ++kk) zr[nj][kk] = *(const short8*)(Z + zAddr[nj][kk]);
#pragma unroll
    for (int kk = 0; kk < 2; ++kk)
#pragma unroll
      for (int mi = 0; mi < 4; ++mi)
#pragma unroll
        for (int nj = 0; nj < 2; ++nj)
          acc[mi][nj] = __builtin_amdgcn_mfma_f32_32x32x16_bf16(
              cf[mi][kk], zr[nj][kk], acc[mi][nj], 0, 0, 0);
  };
  auto EPILOGUE = [&](int chunk) {
    const int cfb0 = cbase + chunk * CTILE + wc * 128 + l5 * 4;
#pragma unroll
    for (int nj = 0; nj < 2; ++nj) {
#pragma unroll
      for (int mi = 0; mi < 4; ++mi) {
#pragma unroll
        for (int rq = 0; rq < 4; ++rq) {
          const float v0 = acc[mi][nj][4 * rq + 0];
          const float v1 = acc[mi][nj][4 * rq + 1];
          const float v2 = acc[mi][nj][4 * rq + 2];
          const float v3 = acc[mi][nj][4 * rq + 3];
          const float gmax = fmaxf(fmaxf(v0, v1), fmaxf(v2, v3));
          // must be !(g <= t): tminf is NaN while table has empty slots ->
          // always enter ((g > NaN) would starve; R2 bug family).
          if (!(gmax <= tminf[nj])) {
#pragma unroll
            for (int ri = 0; ri < 4; ++ri) {
              const int r = 4 * rq + ri;
              const float v = acc[mi][nj][r];
              if (!(v <= tminf[nj])) {
                const unsigned idx = (unsigned)(cfb0 + mi * 32 + (r & 3) + ((r >> 2) << 3));
                const unsigned key = (f2sortable(v) & ~0xFFFu) | idx;
                if (key > tk[nj][0]) {         // replace current min, keep sorted
                  unsigned cur = key;
#pragma unroll
                  for (int q = 0; q < 7; ++q) {
                    const unsigned a = tk[nj][q + 1];
                    tk[nj][q] = (a < cur) ? a : cur;
                    cur       = (a < cur) ? cur : a;
                  }
                  tk[nj][7] = cur;
                  tminf[nj] = sortable2f(tk[nj][0] & ~0xFFFu);
                }
              }
            }
          }
          acc[mi][nj][4 * rq + 0] = 0.f;
          acc[mi][nj][4 * rq + 1] = 0.f;
          acc[mi][nj][4 * rq + 2] = 0.f;
          acc[mi][nj][4 * rq + 3] = 0.f;
        }
      }
    }
  };

  // prologue: stage body 0 -> buf0; advance to body 1
  STAGE(0);
  ADV(0);
  __syncthreads();

  for (int b = 0; b < BODIES; b += 2) {
    // even body: stage b+1 -> buf1, compute buf0
    STAGE(1);
    ADV(b + 1);
    COMPUTE(0);
    __syncthreads();

    // odd body: stage b+2 -> buf0 (if any), compute buf1
    if (b + 2 < BODIES) {
      STAGE(0);
      ADV(b + 2);
    }
    COMPUTE(1);
    if ((b & 31) == 30) EPILOGUE((b + 1) >> 5);   // chunks end at odd bodies 31/63
    __syncthreads();
  }

  // merge: per z row 4 contributors (wc x l5) x 8 keys -> LDS, then top-8 scan
  unsigned* mrg = (unsigned*)smem;     // [256][33] u32 = 33.8 KB
  {
    const int slotw = (wc * 2 + l5) * 8;
#pragma unroll
    for (int nj = 0; nj < 2; ++nj) {
      const int zrow = wz * 64 + nj * 32 + l31;
#pragma unroll
      for (int q = 0; q < 8; ++q) mrg[zrow * 33 + slotw + q] = tk[nj][q];
    }
  }
  __syncthreads();
  if (tid < MTILE) {
    const unsigned* c = mrg + tid * 33;
    unsigned top[8];
#pragma unroll
    for (int p = 0; p < 8; ++p) top[p] = 0u;
    unsigned tmin = 0u;
    for (int q0 = 0; q0 < 32; ++q0) {
      const unsigned k = c[(q0 + tid) & 31];   // rotate to spread banks
      if (k > tmin) {
        int ms = 0;
        unsigned mv = top[0];
#pragma unroll
        for (int q = 1; q < 8; ++q) { if (top[q] < mv) { mv = top[q]; ms = q; } }
#pragma unroll
        for (int q = 0; q < 8; ++q) top[q] = (q == ms) ? k : top[q];
        mv = top[0];
#pragma unroll
        for (int q = 1; q < 8; ++q) mv = (top[q] < mv) ? top[q] : mv;
        tmin = mv;
      }
    }
    unsigned* dst = part + ((size_t)(rbase + tid) * NS + split) * 8;
#pragma unroll
    for (int p = 0; p < 8; ++p) dst[p] = top[p];
  }
}

// ---------------- Kernel 3: merge splits, softmax, gather E, gate ----------------
template<int NSP>
__global__ __launch_bounds__(256)
void k_gate(const unsigned* __restrict__ part, const float* __restrict__ target,
            const float* __restrict__ E, float* __restrict__ out) {
  constexpr int NK = NSP * 8;
  const int row = blockIdx.x;
  const int t = threadIdx.x;
  __shared__ float s_alpha[8];
  __shared__ int s_idx[8];
  __shared__ unsigned s_key[8];

  if (t < NK) {
    unsigned k = part[(size_t)row * NK + t];
#pragma unroll
    for (int p = 0; p < 8; ++p) {
      unsigned m = k;
#pragma unroll
      for (int off = NK / 2; off > 0; off >>= 1) {
        const unsigned o = __shfl_xor(m, off, NK);
        m = (m > o) ? m : o;
      }
      if (k == m) { s_key[p] = k; k = 0u; }  // keys distinct (idx in low bits)
    }
  }
  __syncthreads();
  if (t < 8) {
    const unsigned key = s_key[t];
    const float val  = 10.0f * sortable2f(key & ~0xFFFu);
    const float vmax = 10.0f * sortable2f(s_key[0] & ~0xFFFu);
    const float e = expf(val - vmax);
    float s = e;
#pragma unroll
    for (int off = 4; off > 0; off >>= 1) s += __shfl_xor(s, off, 8);
    s_alpha[t] = e / s;
    s_idx[t] = (int)(key & 0xFFFu);
  }
  __syncthreads();

  float4 g = {0.f, 0.f, 0.f, 0.f};
#pragma unroll
  for (int p = 0; p < 8; ++p) {
    const float a = s_alpha[p];
    const float4 e4 = ((const float4*)E)[(size_t)s_idx[p] * 256 + t];
    g.x += a * e4.x;
    g.y += a * e4.y;
    g.z += a * e4.z;
    g.w += a * e4.w;
  }
  const float4 tg = ((const float4*)target)[(size_t)row * 256 + t];
  float4 o;
  o.x = tg.x * (1.f + g.x);
  o.y = tg.y * (1.f + g.y);
  o.z = tg.z * (1.f + g.z);
  o.w = tg.w * (1.f + g.w);
  ((float4*)out)[(size_t)row * 256 + t] = o;
}

extern "C" void kernel_launch(void* const* d_in, const int* in_sizes, int n_in,
                              void* d_out, int out_size, void* d_ws, size_t ws_size,
                              hipStream_t stream) {
  const float* z      = (const float*)d_in[0];
  const float* target = (const float*)d_in[1];
  const float* cb     = (const float*)d_in[2];
  const float* E      = (const float*)d_in[3];
  float* out = (float*)d_out;

  // d_out doubles as scratch for the bf16 normalized matrices (dead before k_gate writes)
  unsigned short* zf  = (unsigned short*)d_out;                       // 32 MB
  unsigned short* cbf = (unsigned short*)((char*)d_out + 33554432);   // 8 MB @ +32MB
  unsigned* part = (unsigned*)d_ws;                                   // 4 MB

  k_normalize<<<dim3(M_ROWS + K_CB), dim3(256), 0, stream>>>(z, cb, zf, cbf);
  k_gemm_topk<<<dim3(MBLOCKS * NS), dim3(512), 0, stream>>>(zf, cbf, part);
  k_gate<NS><<<dim3(M_ROWS), dim3(256), 0, stream>>>(part, target, E, out);
}